// Round 13
// baseline (167.858 us; speedup 1.0000x reference)
//
#include <hip/hip_runtime.h>
#include <hip/hip_bf16.h>

// Single-head causal attention, B=4 T=4096 C=1024 H=128, fp32 in/out.
//  K1 wtrans: W[1024][128] f32 -> Wt[mat][128][1024] bf16 (transposed)
//  K2 proj:   GEMM BM=64 BN=128 BK=64, 64x64 wave-tiles (4 accs), 128-thr wgs,
//             grid 768, padded 0-conflict LDS, A+B register prefetch (R12).
//  K3 attn:   split-K causal attention (<=4 key-tiles/item, NWORK=272),
//             S^T = K Q^T, in-lane softmax, P->A-frag via dword shuffles.
//             Staging via global_load_lds w16 + addr-side XOR (R7-measured
//             43 us; padded VGPR staging measured 50.8 us in R12 -- the async
//             DMA beats 0-conflict staging for this short K-loop).
//             Partials: bf16 Opart + f32 Lpart plain stores (NO atomics).
//  K4 reduce: sum bf16 partials over splits, normalize, write f32 out.

#define TSEQ 4096
#define NBATCH 4
#define CEMB 1024
#define HS 128
#define NWORK 272   // sum over q=0..31 of ceil((q+1)/2)

typedef float  f32x4  __attribute__((ext_vector_type(4)));
typedef float  f32x16 __attribute__((ext_vector_type(16)));
typedef __bf16 bf16x4 __attribute__((ext_vector_type(4)));
typedef __bf16 bf16x8 __attribute__((ext_vector_type(8)));
typedef int    i32x2  __attribute__((ext_vector_type(2)));
typedef int    i32x4  __attribute__((ext_vector_type(4)));

__device__ __forceinline__ __bf16 f2b(float f) { return (__bf16)f; }
__device__ __forceinline__ float fexp2(float f) { return __builtin_amdgcn_exp2f(f); }

__device__ __forceinline__ void gl_lds16(const void* g, void* l) {
  __builtin_amdgcn_global_load_lds(
      (__attribute__((address_space(1))) void*)(g),
      (__attribute__((address_space(3))) void*)(l), 16, 0, 0);
}

// ---------------------------------------------------------------------------
__global__ void wtrans_kernel(const float* __restrict__ Wq,
                              const float* __restrict__ Wk,
                              const float* __restrict__ Wv,
                              __bf16* __restrict__ Wt) {
  const float* W = (blockIdx.y == 0) ? Wq : (blockIdx.y == 1) ? Wk : Wv;
  int g  = blockIdx.x * 256 + threadIdx.x;
  int n  = g & 127;
  int k0 = (g >> 7) * 8;
  bf16x8 v;
#pragma unroll
  for (int i = 0; i < 8; ++i) v[i] = f2b(W[(size_t)(k0 + i) * HS + n]);
  *(bf16x8*)(Wt + (size_t)blockIdx.y * HS * CEMB + (size_t)n * CEMB + k0) = v;
}

// ---------------------------------------------------------------------------
// K2: projection GEMM v8 (R12-certified). grid 768 x 128 thr.
__global__ __launch_bounds__(128)
void proj_kernel(const float* __restrict__ x, const __bf16* __restrict__ Wt,
                 __bf16* __restrict__ qb, __bf16* __restrict__ kb,
                 __bf16* __restrict__ vt) {
  __shared__ __align__(16) __bf16 As[64 * 72];    // x tile  [64 m][64 k] pad +8
  __shared__ __align__(16) __bf16 Bs[128 * 72];   // Wt tile [128 n][64 k] pad +8

  const int tid  = threadIdx.x;
  const int lane = tid & 63;
  const int w    = tid >> 6;        // 0..1
  const int l31  = lane & 31;
  const int half = lane >> 5;

  const int bid   = blockIdx.x;
  const int xcd   = bid & 7;
  const int rest  = bid >> 3;
  const int mat   = rest % 3;
  const int mslab = rest / 3;
  const int m0    = (xcd + 8 * mslab) * 64;
  const __bf16* Wm = Wt + (size_t)mat * HS * CEMB;

  f32x16 acc[2][2];   // [mi][ni]
#pragma unroll
  for (int a = 0; a < 2; ++a)
#pragma unroll
    for (int b = 0; b < 2; ++b)
#pragma unroll
      for (int r = 0; r < 16; ++r) acc[a][b][r] = 0.f;

  const int srow = tid >> 3;    // 0..15 (16 rows per pass)
  const int soff = tid & 7;     // 16B unit within a 128B row

  f32x4  pa[4][2];
  bf16x8 pb[8];
#pragma unroll
  for (int i = 0; i < 4; ++i) {
    const float* p = x + (size_t)(m0 + srow + 16 * i) * CEMB + soff * 8;
    pa[i][0] = *(const f32x4*)p;
    pa[i][1] = *(const f32x4*)(p + 4);
  }
#pragma unroll
  for (int i = 0; i < 8; ++i)
    pb[i] = *(const bf16x8*)(Wm + (size_t)(srow + 16 * i) * CEMB + soff * 8);

  for (int ks = 0; ks < CEMB; ks += 64) {
    __syncthreads();
#pragma unroll
    for (int i = 0; i < 4; ++i) {
      bf16x8 h;
#pragma unroll
      for (int j = 0; j < 4; ++j) {
        h[j]     = f2b(pa[i][0][j]);
        h[4 + j] = f2b(pa[i][1][j]);
      }
      *(bf16x8*)(As + (srow + 16 * i) * 72 + soff * 8) = h;
    }
#pragma unroll
    for (int i = 0; i < 8; ++i)
      *(bf16x8*)(Bs + (srow + 16 * i) * 72 + soff * 8) = pb[i];
    __syncthreads();
    if (ks + 64 < CEMB) {
#pragma unroll
      for (int i = 0; i < 4; ++i) {
        const float* p = x + (size_t)(m0 + srow + 16 * i) * CEMB + ks + 64 + soff * 8;
        pa[i][0] = *(const f32x4*)p;
        pa[i][1] = *(const f32x4*)(p + 4);
      }
#pragma unroll
      for (int i = 0; i < 8; ++i)
        pb[i] = *(const bf16x8*)(Wm + (size_t)(srow + 16 * i) * CEMB + ks + 64 + soff * 8);
    }
#pragma unroll
    for (int kc = 0; kc < 4; ++kc) {
      bf16x8 af[2], bf[2];
#pragma unroll
      for (int mi = 0; mi < 2; ++mi)
        af[mi] = *(const bf16x8*)(As + (mi * 32 + l31) * 72 + kc * 16 + half * 8);
#pragma unroll
      for (int ni = 0; ni < 2; ++ni)
        bf[ni] = *(const bf16x8*)(Bs + (64 * w + ni * 32 + l31) * 72 + kc * 16 + half * 8);
#pragma unroll
      for (int mi = 0; mi < 2; ++mi)
#pragma unroll
        for (int ni = 0; ni < 2; ++ni)
          acc[mi][ni] = __builtin_amdgcn_mfma_f32_32x32x16_bf16(
              af[mi], bf[ni], acc[mi][ni], 0, 0, 0);
    }
  }

  const float qscale = 1.4426950408889634f / 32.0f;  // log2e / sqrt(1024)
  if (mat == 0) {
#pragma unroll
    for (int mi = 0; mi < 2; ++mi)
#pragma unroll
      for (int ni = 0; ni < 2; ++ni) {
        int n = 64 * w + ni * 32 + l31;
#pragma unroll
        for (int r = 0; r < 16; ++r) {
          int m = m0 + mi * 32 + (r & 3) + 8 * (r >> 2) + 4 * half;
          qb[(size_t)m * HS + n] = f2b(acc[mi][ni][r] * qscale);
        }
      }
  } else if (mat == 1) {
#pragma unroll
    for (int mi = 0; mi < 2; ++mi)
#pragma unroll
      for (int ni = 0; ni < 2; ++ni) {
        int n = 64 * w + ni * 32 + l31;
#pragma unroll
        for (int r = 0; r < 16; ++r) {
          int m = m0 + mi * 32 + (r & 3) + 8 * (r >> 2) + 4 * half;
          kb[(size_t)m * HS + n] = f2b(acc[mi][ni][r]);
        }
      }
  } else {
    const int bt = m0 >> 12;
#pragma unroll
    for (int mi = 0; mi < 2; ++mi)
#pragma unroll
      for (int ni = 0; ni < 2; ++ni) {
        int n = 64 * w + ni * 32 + l31;
#pragma unroll
        for (int g = 0; g < 4; ++g) {
          bf16x4 pk;
#pragma unroll
          for (int d = 0; d < 4; ++d) pk[d] = f2b(acc[mi][ni][4 * g + d]);
          int tl = ((m0 + mi * 32) & 4095) + 8 * g + 4 * half;
          *(bf16x4*)(vt + ((size_t)bt * HS + n) * TSEQ + tl) = pk;
        }
      }
  }
}

// ---------------------------------------------------------------------------
// K3: split-K causal attention (R7-measured 43 us config). grid (272,4) x 256.
__global__ __launch_bounds__(256)
void attn_kernel(const __bf16* __restrict__ qb, const __bf16* __restrict__ kb,
                 const __bf16* __restrict__ vt,
                 __bf16* __restrict__ Opart, float* __restrict__ Lpart) {
  __shared__ __align__(16) __bf16 Kt[64 * 128];    // [key][dim], addr-swizzled
  __shared__ __align__(16) __bf16 Vtl[128 * 64];   // [dim][key], addr-swizzled

  const int tid   = threadIdx.x;
  const int lane  = tid & 63;
  const int w     = tid >> 6;
  const int l31   = lane & 31;
  const int half  = lane >> 5;
  const int batch = blockIdx.y;
  const int xw    = blockIdx.x;

  int q = 0;
  while (q < 31 && xw >= (((q + 2) * (q + 2)) >> 2)) ++q;
  const int split = xw - (((q + 1) * (q + 1)) >> 2);
  const int ntile = 2 * (q + 1);
  const int nsp   = (q + 2) >> 1;
  const int tps   = (ntile + nsp - 1) / nsp;     // <= 4
  const int it0   = split * tps;
  const int it1   = min(it0 + tps, ntile);

  const int strip0 = q * 128 + w * 32;
  const size_t bbase = (size_t)batch * TSEQ;

  bf16x8 qf[8];
  {
    const __bf16* qr = qb + (bbase + strip0 + l31) * HS + half * 8;
#pragma unroll
    for (int kc = 0; kc < 8; ++kc) qf[kc] = *(const bf16x8*)(qr + kc * 16);
  }

  f32x16 o[4];
#pragma unroll
  for (int nt = 0; nt < 4; ++nt)
#pragma unroll
    for (int r = 0; r < 16; ++r) o[nt][r] = 0.f;
  float lsum = 0.f;

  for (int it = it0; it < it1; ++it) {
    const int c0 = it * 64;
    __syncthreads();
    // ---- DMA stage K (16 KB) + V (16 KB), swizzle on the address side ----
#pragma unroll
    for (int i = 0; i < 4; ++i) {
      int ck = i * 4 + w;                       // chunk 0..15
      {
        int r  = 4 * ck + (lane >> 4);          // key row
        int u1 = lane & 15;
        int u  = (u1 & 8) | ((u1 & 7) ^ (r & 7));
        gl_lds16(kb + (bbase + c0 + r) * HS + u * 8, &Kt[ck * 512]);
      }
      {
        int d  = 8 * ck + (lane >> 3);          // dim row
        int u1 = lane & 7;
        int u  = u1 ^ (d & 7);
        gl_lds16(vt + ((size_t)batch * HS + d) * TSEQ + c0 + u * 8, &Vtl[ck * 512]);
      }
    }
    __syncthreads();

    if (c0 <= strip0 + 31) {
      i32x2 pkt[2][4];
#pragma unroll
      for (int t = 0; t < 2; ++t)
#pragma unroll
        for (int j = 0; j < 4; ++j) pkt[t][j] = (i32x2){0, 0};

#pragma unroll
      for (int t = 0; t < 2; ++t) {
        if (c0 + t * 32 <= strip0 + 31) {
          // ---- S^T = K Q^T: lane's col = q-row = l31, row = key ----
          f32x16 s;
#pragma unroll
          for (int r = 0; r < 16; ++r) s[r] = 0.f;
#pragma unroll
          for (int kc = 0; kc < 8; ++kc) {
            int u  = 2 * kc + half;
            int up = (u & 8) | ((u & 7) ^ (l31 & 7));
            bf16x8 kf = *(const bf16x8*)(&Kt[(t * 32 + l31) * 128 + up * 8]);
            s = __builtin_amdgcn_mfma_f32_32x32x16_bf16(kf, qf[kc], s, 0, 0, 0);
          }
          if (c0 + t * 32 + 31 > strip0) {      // diagonal tile: mask
#pragma unroll
            for (int r = 0; r < 16; ++r) {
              int key = c0 + t * 32 + (r & 3) + 8 * (r >> 2) + 4 * half;
              if (key > strip0 + l31) s[r] = -INFINITY;
            }
          }
          float p[16], ps = 0.f;
#pragma unroll
          for (int r = 0; r < 16; ++r) { p[r] = fexp2(s[r]); ps += p[r]; }
          lsum += ps;
#pragma unroll
          for (int j = 0; j < 4; ++j) {
            bf16x4 t4;
#pragma unroll
            for (int d = 0; d < 4; ++d) t4[d] = f2b(p[4 * j + d]);
            pkt[t][j] = __builtin_bit_cast(i32x2, t4);
          }
        }
      }
      // ---- P^T -> A-frag via cross-half dword shuffles; O += P V ----
#pragma unroll
      for (int kk = 0; kk < 4; ++kk) {
        int t = kk >> 1, lo = (kk & 1) * 2;
        i32x2 a = pkt[t][lo], b = pkt[t][lo + 1];
        i32x2 ra, rb;
        ra.x = __shfl_xor(a.x, 32); ra.y = __shfl_xor(a.y, 32);
        rb.x = __shfl_xor(b.x, 32); rb.y = __shfl_xor(b.y, 32);
        i32x4 af4;
        af4.x = half ? rb.x : a.x;
        af4.y = half ? rb.y : a.y;
        af4.z = half ? b.x  : ra.x;
        af4.w = half ? b.y  : ra.y;
        bf16x8 af = __builtin_bit_cast(bf16x8, af4);
#pragma unroll
        for (int nt = 0; nt < 4; ++nt) {
          int up = (2 * kk + half) ^ (l31 & 7);
          bf16x8 vf = *(const bf16x8*)(&Vtl[(nt * 32 + l31) * 64 + up * 8]);
          o[nt] = __builtin_amdgcn_mfma_f32_32x32x16_bf16(af, vf, o[nt], 0, 0, 0);
        }
      }
    }
  }

  const size_t widx = (size_t)batch * NWORK + xw;
  __bf16* Op = Opart + widx * (128 * 128);
#pragma unroll
  for (int r = 0; r < 16; ++r) {
    int rloc = w * 32 + 4 * half + (r & 3) + 8 * (r >> 2);
#pragma unroll
    for (int nt = 0; nt < 4; ++nt)
      Op[rloc * 128 + nt * 32 + l31] = f2b(o[nt][r]);
  }
  lsum += __shfl_xor(lsum, 32);
  if (half == 0) Lpart[widx * 128 + w * 32 + l31] = lsum;
}

// ---------------------------------------------------------------------------
// K4: reduce bf16 partials + normalize. grid (512, 4) x 256 thr.
__global__ __launch_bounds__(256)
void reduce_kernel(const __bf16* __restrict__ Opart, const float* __restrict__ Lpart,
                   float* __restrict__ out) {
  const int batch = blockIdx.y;
  const int rowg  = blockIdx.x * 8 + (threadIdx.x >> 5);
  const int q = rowg >> 7;
  const int nsp = (q + 2) >> 1;
  const int off = ((q + 1) * (q + 1)) >> 2;
  const size_t wbase = (size_t)batch * NWORK + off;
  const int row128 = rowg & 127;
  const int c0 = (threadIdx.x & 31) * 4;

  float l = 0.f;
  for (int s = 0; s < nsp; ++s) l += Lpart[(wbase + s) * 128 + row128];
  const float inv = 1.0f / l;

  const __bf16* op = Opart + wbase * (128 * 128) + row128 * 128 + c0;
  f32x4 a = {0.f, 0.f, 0.f, 0.f};
  for (int s = 0; s < nsp; ++s) {
    bf16x4 v = *(const bf16x4*)(op + (size_t)s * 128 * 128);
#pragma unroll
    for (int j = 0; j < 4; ++j) a[j] += (float)v[j];
  }
  a *= inv;
  *(f32x4*)(out + ((size_t)batch * TSEQ + rowg) * HS + c0) = a;
}

// ---------------------------------------------------------------------------
extern "C" void kernel_launch(void* const* d_in, const int* in_sizes, int n_in,
                              void* d_out, int out_size, void* d_ws, size_t ws_size,
                              hipStream_t stream) {
  const float* x  = (const float*)d_in[0];
  const float* Wq = (const float*)d_in[1];
  const float* Wk = (const float*)d_in[2];
  const float* Wv = (const float*)d_in[3];
  float* out = (float*)d_out;

  char* ws = (char*)d_ws;
  // Wt 768K | qb 4M | kb 4M | vt 4M | Opart(bf16) 35.65M | Lpart 557K
  __bf16* Wt = (__bf16*)ws;
  __bf16* qb = (__bf16*)(ws + 786432);
  __bf16* kb = (__bf16*)(ws + 786432 + 4194304);
  __bf16* vt = (__bf16*)(ws + 786432 + 2 * 4194304);
  __bf16* Opart = (__bf16*)(ws + 786432 + 3 * 4194304);
  float*  Lpart = (float*)(ws + 786432 + 3 * 4194304 +
                           (size_t)NBATCH * NWORK * 128 * 128 * 2);

  wtrans_kernel<<<dim3(64, 3), 256, 0, stream>>>(Wq, Wk, Wv, Wt);
  proj_kernel<<<dim3(768), 128, 0, stream>>>(x, Wt, qb, kb, vt);
  attn_kernel<<<dim3(NWORK, NBATCH), 256, 0, stream>>>(qb, kb, vt, Opart, Lpart);
  reduce_kernel<<<dim3(512, NBATCH), 256, 0, stream>>>(Opart, Lpart, out);
}